// Round 1
// baseline (1766.219 us; speedup 1.0000x reference)
//
#include <hip/hip_runtime.h>

// VQ: B=131072 rows, K=4096 codes, D=64, fp32.
// out = [B*D floats quantized_st][1 float loss]
constexpr int Bn = 131072;
constexpr int Kn = 4096;
constexpr int Dn = 64;

__global__ void vq_zero(float* __restrict__ loss_acc) {
    *loss_acc = 0.0f;
}

__global__ __launch_bounds__(256) void vq_main(const float* __restrict__ x,
                                               const float* __restrict__ cb,
                                               float* __restrict__ out,
                                               float* __restrict__ loss_acc) {
    __shared__ float scnorm[Kn];
    const int tid = threadIdx.x;

    // ---- Phase 1: codebook squared norms into LDS (coalesced) ----
    // cb flat as float4: 65536 vectors; 256 threads x 256 iters.
    // Each aligned 16-lane group covers exactly one code (64 floats).
    {
        const float4* cb4 = (const float4*)cb;
        #pragma unroll 4
        for (int i = 0; i < (Kn * Dn / 4) / 256; ++i) {
            const int f = i * 256 + tid;
            const float4 v = cb4[f];
            float s = fmaf(v.x, v.x, fmaf(v.y, v.y, fmaf(v.z, v.z, v.w * v.w)));
            s += __shfl_xor(s, 1);
            s += __shfl_xor(s, 2);
            s += __shfl_xor(s, 4);
            s += __shfl_xor(s, 8);
            if ((tid & 15) == 0) scnorm[f >> 4] = s;
        }
    }
    __syncthreads();

    // ---- Phase 2: per-row argmin over K codes ----
    const long row = (long)blockIdx.x * 256 + tid;
    float4 xv[16];
    {
        const float4* xr = (const float4*)(x + row * Dn);
        #pragma unroll
        for (int j = 0; j < 16; ++j) xv[j] = xr[j];
    }

    float best = 3.4e38f;
    int bidx = 0;
    for (int k = 0; k < Kn; ++k) {
        // Block-uniform address -> expect scalar (s_load) codebook reads.
        const float4* c4 = (const float4*)(cb + (size_t)k * Dn);
        float a0 = 0.f, a1 = 0.f, a2 = 0.f, a3 = 0.f;
        #pragma unroll
        for (int j = 0; j < 16; ++j) {
            const float4 c = c4[j];
            a0 = fmaf(xv[j].x, c.x, a0);
            a1 = fmaf(xv[j].y, c.y, a1);
            a2 = fmaf(xv[j].z, c.z, a2);
            a3 = fmaf(xv[j].w, c.w, a3);
        }
        const float dot = (a0 + a1) + (a2 + a3);
        const float dist = fmaf(-2.0f, dot, scnorm[k]);
        if (dist < best) { best = dist; bidx = k; }  // strict < : first-min, matches np.argmin
    }

    // ---- Phase 3: gather, straight-through output, loss partial ----
    const float4* q4 = (const float4*)(cb + (size_t)bidx * Dn);
    float4* o4 = (float4*)(out + row * Dn);
    float ls = 0.f;
    #pragma unroll
    for (int j = 0; j < 16; ++j) {
        const float4 q = q4[j];
        const float4 xx = xv[j];
        const float dx = q.x - xx.x;
        const float dy = q.y - xx.y;
        const float dz = q.z - xx.z;
        const float dw = q.w - xx.w;
        float4 o;
        o.x = xx.x + dx;  // match reference: x + (q - x)
        o.y = xx.y + dy;
        o.z = xx.z + dz;
        o.w = xx.w + dw;
        o4[j] = o;
        ls = fmaf(dx, dx, ls);
        ls = fmaf(dy, dy, ls);
        ls = fmaf(dz, dz, ls);
        ls = fmaf(dw, dw, ls);
    }
    // wave reduction (64 lanes)
    #pragma unroll
    for (int m = 1; m < 64; m <<= 1) ls += __shfl_xor(ls, m);
    if ((tid & 63) == 0) atomicAdd(loss_acc, ls);
}

__global__ void vq_final(float* __restrict__ loss_acc) {
    *loss_acc = *loss_acc * (1.25f / (float)(Bn * Dn));
}

extern "C" void kernel_launch(void* const* d_in, const int* in_sizes, int n_in,
                              void* d_out, int out_size, void* d_ws, size_t ws_size,
                              hipStream_t stream) {
    const float* x  = (const float*)d_in[0];
    const float* cb = (const float*)d_in[1];
    float* out  = (float*)d_out;
    float* loss = out + (size_t)Bn * Dn;

    vq_zero<<<1, 1, 0, stream>>>(loss);
    vq_main<<<Bn / 256, 256, 0, stream>>>(x, cb, out, loss);
    vq_final<<<1, 1, 0, stream>>>(loss);
}